// Round 9
// baseline (308.718 us; speedup 1.0000x reference)
//
#include <hip/hip_runtime.h>
#include <hip/hip_bf16.h>

typedef __hip_bfloat16 bf16;
typedef __attribute__((ext_vector_type(8))) short short8;
typedef __attribute__((ext_vector_type(4))) float float4v;

constexpr int Nn = 8, Cc = 512, Tt = 4096, Gg = 32, CPG = 16;
constexpr float EPS = 1e-5f;

__device__ __forceinline__ float b2f(bf16 x){ return __bfloat162float(x); }
__device__ __forceinline__ bf16  f2b(float x){ return __float2bfloat16(x); }
__device__ __forceinline__ short f2s(float x){
    union { bf16 b; short s; } u; u.b = f2b(x); return u.s;
}
__device__ __forceinline__ float s2f(short x){
    union { short s; bf16 b; } u; u.s = x; return b2f(u.b);
}

__device__ __forceinline__ float stride_val(const void* sp){
    int si = *(const int*)sp;
    if (si >= 1 && si <= 100000) return (float)si;
    float sf = *(const float*)sp;
    if (sf >= 0.5f && sf <= 1.0e5f) return sf;
    return 8.0f;
}

// async global->LDS, 16B per lane; LDS dest = wave-uniform base + lane*16
__device__ __forceinline__ void gld16(const void* g, void* l){
    __builtin_amdgcn_global_load_lds(
        (const __attribute__((address_space(1))) unsigned int*)g,
        (__attribute__((address_space(3))) unsigned int*)l, 16, 0, 0);
}

// ---- P1: transpose feat fp32 [n][i][t] -> ftr bf16 [n][t+1][i] (pad rows 0,4097) ----
__global__ void k_transpose(const float* __restrict__ feat, bf16* __restrict__ ftr){
    __shared__ float L[64 * 65];
    int t0 = blockIdx.x * 64, i0 = blockIdx.y * 64, n = blockIdx.z;
    int tid = threadIdx.x;
    const float* fb = feat + ((size_t)n * Cc + i0) * Tt + t0;
    #pragma unroll
    for (int it = 0; it < 4; ++it){
        int p = tid + it * 256;
        int i = p >> 4, t4 = (p & 15) * 4;
        float4v v = *(const float4v*)&fb[(size_t)i * Tt + t4];
        L[(t4 + 0) * 65 + i] = v.x;
        L[(t4 + 1) * 65 + i] = v.y;
        L[(t4 + 2) * 65 + i] = v.z;
        L[(t4 + 3) * 65 + i] = v.w;
    }
    __syncthreads();
    #pragma unroll
    for (int it = 0; it < 2; ++it){
        int p = tid + it * 256;
        int t = p >> 3, s = p & 7;
        short8 sv;
        #pragma unroll
        for (int j = 0; j < 8; ++j) sv[j] = f2s(L[t * 65 + s * 8 + j]);
        *(short8*)&ftr[((size_t)n * 4098 + t0 + t + 1) * Cc + i0 + s * 8] = sv;
    }
}

// ---- merged small kernels: weight cvt x2, ftr zero-pad, offset init, stat zero ----
__global__ void k_misc(const float* __restrict__ cw, const float* __restrict__ dw,
        bf16* __restrict__ wtc, bf16* __restrict__ wtd, bf16* __restrict__ ftr,
        const float* __restrict__ ob, float* __restrict__ offset,
        float* __restrict__ gstat){
    int p = blockIdx.x * 256 + threadIdx.x;      // 786432
    {
        int k = p >> 18, rest = p & 262143;
        wtc[p] = f2b(cw[(size_t)rest * 3 + k]);
        wtd[p] = f2b(dw[(size_t)rest * 3 + k]);
    }
    if (p < 65536) offset[p] = ob[(p >> 12) & 1];
    if (p < 8192){
        int n = p >> 10, r = (p >> 9) & 1, i = p & 511;
        ftr[((size_t)n * 4098 + (r ? 4097 : 0)) * Cc + i] = f2b(0.f);
    }
    if (p < 512) gstat[p] = 0.f;
}

// =====================================================================
// conv1 GEMM: R6-exact BK=32 core (proven best for conv1g)
// LDS(r,s) holds G(r, s ^ ((r>>1)&3)); frag read uses same xor.
// =====================================================================
__global__ __launch_bounds__(256, 4) void k_conv1g(const bf16* __restrict__ ftr,
        const bf16* __restrict__ wtc, const float* __restrict__ bias, bf16* __restrict__ ht,
        float* __restrict__ gsum, float* __restrict__ gss){
    __shared__ __align__(16) short As[128 * 32];
    __shared__ __align__(16) short Bs[128 * 32];
    __shared__ float Lt[32 * 132];
    __shared__ float gred[16];
    int t0 = blockIdx.x * 128, o0 = blockIdx.y * 128, n = blockIdx.z;
    int tid = threadIdx.x, wid = tid >> 6, lane = tid & 63;
    int quad = lane >> 4, l15 = lane & 15;
    int rlo  = lane >> 2;                            // staging row within 16
    int colo = 8 * ((lane & 3) ^ ((lane >> 3) & 3)); // swizzled staging col (shorts)
    int sgf  = 8 * (quad ^ ((lane >> 1) & 3));       // swizzled frag col (shorts)

    float4v acc[2][8];
    #pragma unroll
    for (int m = 0; m < 2; ++m)
        #pragma unroll
        for (int f = 0; f < 8; ++f) acc[m][f] = (float4v){0.f,0.f,0.f,0.f};

    const short* ABp = (const short*)wtc + (size_t)o0 * 512;
    const short* BBp = (const short*)ftr + ((size_t)n * 4098 + t0) * 512;
    int r0 = wid * 32;

    for (int tap = 0; tap < 3; ++tap){
        const short* Ab = ABp + (size_t)tap * 262144;
        const short* Bb = BBp + (size_t)tap * 512;
        for (int ic = 0; ic < 512; ic += 32){
            gld16(Ab + (size_t)(r0 + rlo)      * 512 + ic + colo, As + r0 * 32);
            gld16(Ab + (size_t)(r0 + 16 + rlo) * 512 + ic + colo, As + (r0 + 16) * 32);
            gld16(Bb + (size_t)(r0 + rlo)      * 512 + ic + colo, Bs + r0 * 32);
            gld16(Bb + (size_t)(r0 + 16 + rlo) * 512 + ic + colo, Bs + (r0 + 16) * 32);
            __syncthreads();
            short8 a0 = *(const short8*)&As[(r0 + l15) * 32 + sgf];
            short8 a1 = *(const short8*)&As[(r0 + 16 + l15) * 32 + sgf];
            #pragma unroll
            for (int f = 0; f < 8; ++f){
                short8 b = *(const short8*)&Bs[(f * 16 + l15) * 32 + sgf];
                acc[0][f] = __builtin_amdgcn_mfma_f32_16x16x32_bf16(a0, b, acc[0][f], 0, 0, 0);
                acc[1][f] = __builtin_amdgcn_mfma_f32_16x16x32_bf16(a1, b, acc[1][f], 0, 0, 0);
            }
            __syncthreads();
        }
    }
    float gs = 0.f, gq = 0.f;
    int sg = tid & 15;
    #pragma unroll
    for (int pass = 0; pass < 4; ++pass){
        __syncthreads();
        #pragma unroll
        for (int m = 0; m < 2; ++m){
            #pragma unroll
            for (int fi = 0; fi < 2; ++fi){
                int f = pass * 2 + fi;
                int tl = fi * 16 + l15;
                int ob = wid * 32 + m * 16 + quad * 4;
                #pragma unroll
                for (int r = 0; r < 4; ++r)
                    Lt[tl * 132 + ob + r] = acc[m][f][r] + bias[o0 + ob + r];
            }
        }
        __syncthreads();
        #pragma unroll
        for (int it = 0; it < 2; ++it){
            int p = tid + it * 256;
            int tl = p >> 4, s = p & 15;
            short8 sv;
            #pragma unroll
            for (int j = 0; j < 8; ++j){
                float fv = Lt[tl * 132 + s * 8 + j];
                gs += fv; gq += fv * fv;
                sv[j] = f2s(fv);
            }
            *(short8*)&ht[((size_t)n * Tt + t0 + pass * 32 + tl) * Cc + o0 + s * 8] = sv;
        }
    }
    if (tid < 16) gred[tid] = 0.f;
    __syncthreads();
    atomicAdd(&gred[(sg >> 1) * 2 + 0], gs);
    atomicAdd(&gred[(sg >> 1) * 2 + 1], gq);
    __syncthreads();
    if (tid < 8){
        int blk = n * 32 + (o0 >> 4) + tid;
        atomicAdd(&gsum[blk], gred[tid * 2 + 0]);
        atomicAdd(&gss[blk],  gred[tid * 2 + 1]);
    }
}

// ---- GN apply + relu, in place on ht (stats from fused sums) ----
__global__ void k_gnapply2(bf16* __restrict__ ht, const float* __restrict__ gsum,
        const float* __restrict__ gss, const float* __restrict__ gamma,
        const float* __restrict__ beta){
    int p = blockIdx.x * 256 + threadIdx.x;
    int s = p & 63, row = p >> 6;             // row = n*4096+t
    int n = row >> 12;
    int ib = s * 8;
    int blk = n * 32 + (ib >> 4);
    const float inv = 1.f / (float)(CPG * Tt);
    float mu = gsum[blk] * inv;
    float rs = rsqrtf(gss[blk] * inv - mu * mu + EPS);
    short8 v = *(short8*)&ht[(size_t)row * Cc + ib];
    short8 o;
    #pragma unroll
    for (int j = 0; j < 8; ++j){
        int c = ib + j;
        float f = (s2f(v[j]) - mu) * rs * gamma[c] + beta[c];
        o[j] = f2s(fmaxf(f, 0.f));
    }
    *(short8*)&ht[(size_t)row * Cc + ib] = o;
}

// ---- materialize S0/S2 (gather+lerp, coalesced in i); prep inlined;
//      XCD-contiguity swizzle on t-chunks ----
__global__ void k_sample(const bf16* __restrict__ ht, const float* __restrict__ locs,
        const void* __restrict__ sp, bf16* __restrict__ S0, bf16* __restrict__ S2){
    int n = blockIdx.y;
    int bx = blockIdx.x;
    int t0 = ((((bx & 7) << 5) | (bx >> 3))) << 4;   // bijective on 256 chunks
    int lane = threadIdx.x & 63, slot = threadIdx.x >> 6;
    float s = stride_val(sp);
    const bf16* hb = ht + (size_t)n * Tt * Cc;
    #pragma unroll
    for (int rr = 0; rr < 4; ++rr){
        int t = t0 + slot * 4 + rr;
        int idx = n * Tt + t;
        float l1 = locs[((size_t)n * 2 + 0) * Tt + t];
        float l2 = locs[((size_t)n * 2 + 1) * Tt + t];
        float y1 = (0.9f * l1 + 0.1f * l1) / s;     // match ref GRAD_MUL arithmetic
        float y2 = (0.9f * l2 + 0.1f * l2) / s;
        {
            float pos0 = (float)(t - 1) - y1;
            float p0f = floorf(pos0);
            float w1 = pos0 - p0f;
            int a0 = (int)p0f, a1 = a0 + 1;
            float w0 = (a0 >= 0 && a0 < Tt) ? (1.f - w1) : 0.f;
            float w1v = (a1 >= 0 && a1 < Tt) ? w1 : 0.f;
            int ia0 = min(max(a0, 0), Tt - 1);
            int ia1 = min(max(a1, 0), Tt - 1);
            short8 lo = *(const short8*)&hb[(size_t)ia0 * Cc + lane * 8];
            short8 hi = *(const short8*)&hb[(size_t)ia1 * Cc + lane * 8];
            short8 o;
            #pragma unroll
            for (int j = 0; j < 8; ++j) o[j] = f2s(w0 * s2f(lo[j]) + w1v * s2f(hi[j]));
            *(short8*)&S0[(size_t)idx * Cc + lane * 8] = o;
        }
        {
            float pos2 = (float)(t + 1) + y2;
            float p2f = floorf(pos2);
            float w2 = pos2 - p2f;
            int c0 = (int)p2f, c1 = c0 + 1;
            float w0 = (c0 >= 0 && c0 < Tt) ? (1.f - w2) : 0.f;
            float w1v = (c1 >= 0 && c1 < Tt) ? w2 : 0.f;
            int ic0 = min(max(c0, 0), Tt - 1);
            int ic1 = min(max(c1, 0), Tt - 1);
            short8 lo = *(const short8*)&hb[(size_t)ic0 * Cc + lane * 8];
            short8 hi = *(const short8*)&hb[(size_t)ic1 * Cc + lane * 8];
            short8 o;
            #pragma unroll
            for (int j = 0; j < 8; ++j) o[j] = f2s(w0 * s2f(lo[j]) + w1v * s2f(hi[j]));
            *(short8*)&S2[(size_t)idx * Cc + lane * 8] = o;
        }
    }
}

// =====================================================================
// deform GEMM, pipelined: double-buffered BK=32 chunks, issue-early /
// drain-late with vmcnt(0) (count-immune) + ONE raw barrier per chunk.
// Chunk ch reads buf=ch&1, stages ch+1 into buf^1. Safety:
//  - buf's loads: issued at ch-1, drained by each wave's own vmcnt(0),
//    barrier makes that collective.
//  - buf^1's writes: prior reads of buf^1 (ch-1 frags) are lgkm-complete
//    before each wave's MFMAs, which precede the barrier.
// Worst-case failure is wrong results (harness-caught), not deadlock:
// vmcnt(0) always satisfiable, control flow uniform.
// =====================================================================
__global__ __launch_bounds__(256, 4) void k_deformg(const bf16* __restrict__ S0,
        const bf16* __restrict__ ht, const bf16* __restrict__ S2,
        const bf16* __restrict__ wtd, const float* __restrict__ bias,
        float* __restrict__ out, const float* __restrict__ wout,
        float* __restrict__ oout){
    __shared__ __align__(16) short As[2][128 * 32];
    __shared__ __align__(16) short Bs[2][128 * 32];
    int t0 = blockIdx.x * 128, o0 = blockIdx.y * 128, n = blockIdx.z;
    int tid = threadIdx.x, wid = tid >> 6, lane = tid & 63;
    int quad = lane >> 4, l15 = lane & 15;
    int rlo  = lane >> 2;
    int colo = 8 * ((lane & 3) ^ ((lane >> 3) & 3));
    int sgf  = 8 * (quad ^ ((lane >> 1) & 3));

    float4v acc[2][8];
    #pragma unroll
    for (int m = 0; m < 2; ++m)
        #pragma unroll
        for (int f = 0; f < 8; ++f) acc[m][f] = (float4v){0.f,0.f,0.f,0.f};

    size_t boff = ((size_t)n * Tt + t0) * 512;
    const short* B0p = (const short*)S0 + boff;
    const short* B1p = (const short*)ht + boff;
    const short* B2p = (const short*)S2 + boff;
    const short* ABp = (const short*)wtd + (size_t)o0 * 512;
    int r0 = wid * 32;

    // stage chunk ch (tap = ch>>4, ic = (ch&15)*32) into buffer bf
    #define STAGE_CH(ch, bf) do {                                              \
        int tap_ = (ch) >> 4, ic_ = ((ch) & 15) << 5;                          \
        const short* Ab_ = ABp + (size_t)tap_ * 262144 + ic_;                  \
        const short* Bb_ = (tap_ == 0) ? B0p : ((tap_ == 1) ? B1p : B2p);      \
        Bb_ += ic_;                                                            \
        gld16(Ab_ + (size_t)(r0 + rlo)      * 512 + colo, &As[bf][r0 * 32]);   \
        gld16(Ab_ + (size_t)(r0 + 16 + rlo) * 512 + colo, &As[bf][(r0 + 16) * 32]); \
        gld16(Bb_ + (size_t)(r0 + rlo)      * 512 + colo, &Bs[bf][r0 * 32]);   \
        gld16(Bb_ + (size_t)(r0 + 16 + rlo) * 512 + colo, &Bs[bf][(r0 + 16) * 32]); \
    } while (0)

    STAGE_CH(0, 0);
    #pragma unroll 2
    for (int ch = 0; ch < 48; ++ch){
        int buf = ch & 1;
        asm volatile("s_waitcnt vmcnt(0)" ::: "memory");
        __builtin_amdgcn_s_barrier();
        __builtin_amdgcn_sched_barrier(0);
        if (ch + 1 < 48) STAGE_CH(ch + 1, buf ^ 1);
        short8 a0 = *(const short8*)&As[buf][(r0 + l15) * 32 + sgf];
        short8 a1 = *(const short8*)&As[buf][(r0 + 16 + l15) * 32 + sgf];
        #pragma unroll
        for (int f = 0; f < 8; ++f){
            short8 b = *(const short8*)&Bs[buf][(f * 16 + l15) * 32 + sgf];
            acc[0][f] = __builtin_amdgcn_mfma_f32_16x16x32_bf16(a0, b, acc[0][f], 0, 0, 0);
            acc[1][f] = __builtin_amdgcn_mfma_f32_16x16x32_bf16(a1, b, acc[1][f], 0, 0, 0);
        }
    }
    #undef STAGE_CH
    __syncthreads();

    // epilogue A: relu(acc+bias) -> offset_feat, keep v in acc for scatter
    float* part = (float*)As;   // [2][132] (safe: post-barrier)
    for (int q = tid; q < 264; q += 256) part[q] = 0.f;
    float* ob = out + (size_t)n * Cc * Tt;
    #pragma unroll
    for (int m = 0; m < 2; ++m){
        int ob0 = o0 + wid * 32 + m * 16 + quad * 4;
        #pragma unroll
        for (int r = 0; r < 4; ++r){
            float bs = bias[ob0 + r];
            size_t row = (size_t)(ob0 + r) * Tt;
            #pragma unroll
            for (int f = 0; f < 8; ++f){
                float v = fmaxf(acc[m][f][r] + bs, 0.f);
                acc[m][f][r] = v;
                ob[row + t0 + f * 16 + l15] = v;
            }
        }
    }
    __syncthreads();
    // epilogue B: scatter out-conv; wout read direct (16-way L1 broadcast)
    #pragma unroll
    for (int c = 0; c < 2; ++c){
        float wr[3][2][4];
        #pragma unroll
        for (int m = 0; m < 2; ++m){
            int ob0 = o0 + wid * 32 + m * 16 + quad * 4;
            #pragma unroll
            for (int r = 0; r < 4; ++r){
                const float* wp = wout + (size_t)c * 1536 + (ob0 + r) * 3;
                wr[0][m][r] = wp[0];
                wr[1][m][r] = wp[1];
                wr[2][m][r] = wp[2];
            }
        }
        #pragma unroll
        for (int f = 0; f < 8; ++f){
            #pragma unroll
            for (int k = 0; k < 3; ++k){
                float contrib = 0.f;
                #pragma unroll
                for (int m = 0; m < 2; ++m)
                    #pragma unroll
                    for (int r = 0; r < 4; ++r)
                        contrib += wr[k][m][r] * acc[m][f][r];
                contrib += __shfl_xor(contrib, 16);
                contrib += __shfl_xor(contrib, 32);
                if (quad == 0)
                    atomicAdd(&part[c * 132 + f * 16 + l15 + 2 - k], contrib);
            }
        }
    }
    __syncthreads();
    for (int q = tid; q < 264; q += 256){
        int c = q / 132, tl = q - c * 132;
        if (tl < 130){
            int tg = t0 + tl - 1;
            if (tg >= 0 && tg < Tt)
                atomicAdd(&oout[((size_t)n * 2 + c) * Tt + tg], part[q]);
        }
    }
}

// ================================ HOST ================================
extern "C" void kernel_launch(void* const* d_in, const int* in_sizes, int n_in,
                              void* d_out, int out_size, void* d_ws, size_t ws_size,
                              hipStream_t stream) {
    const float* feat   = (const float*)d_in[0];
    const float* locs   = (const float*)d_in[1];
    const float* conv_w = (const float*)d_in[2];
    const float* conv_b = (const float*)d_in[3];
    const float* gn_g   = (const float*)d_in[4];
    const float* gn_b   = (const float*)d_in[5];
    const float* dcn_w  = (const float*)d_in[6];
    const float* dcn_b  = (const float*)d_in[7];
    const float* out_w  = (const float*)d_in[8];
    const float* out_b  = (const float*)d_in[9];

    float* offset      = (float*)d_out;                        // (8,2,4096) fp32
    float* offset_feat = (float*)d_out + (size_t)Nn * 2 * Tt;  // (8,512,4096) fp32

    constexpr size_t OFF_WTC  = 4096;
    constexpr size_t OFF_WTD  = OFF_WTC + 3 * 512 * 512 * 2;
    constexpr size_t OFF_FTR  = OFF_WTD + 3 * 512 * 512 * 2;
    constexpr size_t OFF_HT   = OFF_FTR + (size_t)8 * 4098 * 512 * 2;
    constexpr size_t OFF_S2   = OFF_HT  + (size_t)8 * 4096 * 512 * 2;

    float* gsum = (float*)d_ws;                       // 256 floats
    float* gss  = (float*)((char*)d_ws + 1024);       // 256 floats

    char* ws = (char*)d_ws;
    bf16* wtc = (bf16*)(ws + OFF_WTC);
    bf16* wtd = (bf16*)(ws + OFF_WTD);
    bf16* ftr = (bf16*)(ws + OFF_FTR);    // reused as S0 after conv1
    bf16* ht  = (bf16*)(ws + OFF_HT);
    bf16* S2  = (bf16*)(ws + OFF_S2);
    bf16* S0  = ftr;

    k_transpose<<<dim3(64, 8, 8), 256, 0, stream>>>(feat, ftr);
    k_misc     <<<3072, 256, 0, stream>>>(conv_w, dcn_w, wtc, wtd, ftr, out_b,
                                          offset, (float*)d_ws);
    k_conv1g   <<<dim3(32, 4, 8), 256, 0, stream>>>(ftr, wtc, conv_b, ht, gsum, gss);
    k_gnapply2 <<<8192, 256, 0, stream>>>(ht, gsum, gss, gn_g, gn_b);
    k_sample   <<<dim3(256, 8), 256, 0, stream>>>(ht, locs, d_in[10], S0, S2);
    k_deformg  <<<dim3(32, 4, 8), 256, 0, stream>>>(S0, ht, S2, wtd, dcn_b,
                                                    offset_feat, out_w, offset);
}

// Round 10
// 299.524 us; speedup vs baseline: 1.0307x; 1.0307x over previous
//
#include <hip/hip_runtime.h>
#include <hip/hip_bf16.h>

typedef __hip_bfloat16 bf16;
typedef __attribute__((ext_vector_type(8))) short short8;
typedef __attribute__((ext_vector_type(4))) float float4v;

constexpr int Nn = 8, Cc = 512, Tt = 4096, Gg = 32, CPG = 16;
constexpr float EPS = 1e-5f;

__device__ __forceinline__ float b2f(bf16 x){ return __bfloat162float(x); }
__device__ __forceinline__ bf16  f2b(float x){ return __float2bfloat16(x); }
__device__ __forceinline__ short f2s(float x){
    union { bf16 b; short s; } u; u.b = f2b(x); return u.s;
}
__device__ __forceinline__ float s2f(short x){
    union { short s; bf16 b; } u; u.s = x; return b2f(u.b);
}

__device__ __forceinline__ float stride_val(const void* sp){
    int si = *(const int*)sp;
    if (si >= 1 && si <= 100000) return (float)si;
    float sf = *(const float*)sp;
    if (sf >= 0.5f && sf <= 1.0e5f) return sf;
    return 8.0f;
}

// async global->LDS, 16B per lane; LDS dest = wave-uniform base + lane*16
__device__ __forceinline__ void gld16(const void* g, void* l){
    __builtin_amdgcn_global_load_lds(
        (const __attribute__((address_space(1))) unsigned int*)g,
        (__attribute__((address_space(3))) unsigned int*)l, 16, 0, 0);
}

// ---- P1: transpose feat fp32 [n][i][t] -> ftr bf16 [n][t+1][i] (pad rows 0,4097) ----
__global__ void k_transpose(const float* __restrict__ feat, bf16* __restrict__ ftr){
    __shared__ float L[64 * 65];
    int t0 = blockIdx.x * 64, i0 = blockIdx.y * 64, n = blockIdx.z;
    int tid = threadIdx.x;
    const float* fb = feat + ((size_t)n * Cc + i0) * Tt + t0;
    #pragma unroll
    for (int it = 0; it < 4; ++it){
        int p = tid + it * 256;
        int i = p >> 4, t4 = (p & 15) * 4;
        float4v v = *(const float4v*)&fb[(size_t)i * Tt + t4];
        L[(t4 + 0) * 65 + i] = v.x;
        L[(t4 + 1) * 65 + i] = v.y;
        L[(t4 + 2) * 65 + i] = v.z;
        L[(t4 + 3) * 65 + i] = v.w;
    }
    __syncthreads();
    #pragma unroll
    for (int it = 0; it < 2; ++it){
        int p = tid + it * 256;
        int t = p >> 3, s = p & 7;
        short8 sv;
        #pragma unroll
        for (int j = 0; j < 8; ++j) sv[j] = f2s(L[t * 65 + s * 8 + j]);
        *(short8*)&ftr[((size_t)n * 4098 + t0 + t + 1) * Cc + i0 + s * 8] = sv;
    }
}

// ---- merged small kernels: weight cvt x2, ftr zero-pad, offset init, stat zero ----
__global__ void k_misc(const float* __restrict__ cw, const float* __restrict__ dw,
        bf16* __restrict__ wtc, bf16* __restrict__ wtd, bf16* __restrict__ ftr,
        const float* __restrict__ ob, float* __restrict__ offset,
        float* __restrict__ gstat){
    int p = blockIdx.x * 256 + threadIdx.x;      // 786432
    {
        int k = p >> 18, rest = p & 262143;
        wtc[p] = f2b(cw[(size_t)rest * 3 + k]);
        wtd[p] = f2b(dw[(size_t)rest * 3 + k]);
    }
    if (p < 65536) offset[p] = ob[(p >> 12) & 1];
    if (p < 8192){
        int n = p >> 10, r = (p >> 9) & 1, i = p & 511;
        ftr[((size_t)n * 4098 + (r ? 4097 : 0)) * Cc + i] = f2b(0.f);
    }
    if (p < 512) gstat[p] = 0.f;
}

// =====================================================================
// conv1 GEMM: BK=32 core (A/B-proven best for conv1g)
// LDS(r,s) holds G(r, s ^ ((r>>1)&3)); frag read uses same xor.
// =====================================================================
__global__ __launch_bounds__(256, 4) void k_conv1g(const bf16* __restrict__ ftr,
        const bf16* __restrict__ wtc, const float* __restrict__ bias, bf16* __restrict__ ht,
        float* __restrict__ gsum, float* __restrict__ gss){
    __shared__ __align__(16) short As[128 * 32];
    __shared__ __align__(16) short Bs[128 * 32];
    __shared__ float Lt[32 * 132];
    __shared__ float gred[16];
    int t0 = blockIdx.x * 128, o0 = blockIdx.y * 128, n = blockIdx.z;
    int tid = threadIdx.x, wid = tid >> 6, lane = tid & 63;
    int quad = lane >> 4, l15 = lane & 15;
    int rlo  = lane >> 2;                            // staging row within 16
    int colo = 8 * ((lane & 3) ^ ((lane >> 3) & 3)); // swizzled staging col (shorts)
    int sgf  = 8 * (quad ^ ((lane >> 1) & 3));       // swizzled frag col (shorts)

    float4v acc[2][8];
    #pragma unroll
    for (int m = 0; m < 2; ++m)
        #pragma unroll
        for (int f = 0; f < 8; ++f) acc[m][f] = (float4v){0.f,0.f,0.f,0.f};

    const short* ABp = (const short*)wtc + (size_t)o0 * 512;
    const short* BBp = (const short*)ftr + ((size_t)n * 4098 + t0) * 512;
    int r0 = wid * 32;

    for (int tap = 0; tap < 3; ++tap){
        const short* Ab = ABp + (size_t)tap * 262144;
        const short* Bb = BBp + (size_t)tap * 512;
        for (int ic = 0; ic < 512; ic += 32){
            gld16(Ab + (size_t)(r0 + rlo)      * 512 + ic + colo, As + r0 * 32);
            gld16(Ab + (size_t)(r0 + 16 + rlo) * 512 + ic + colo, As + (r0 + 16) * 32);
            gld16(Bb + (size_t)(r0 + rlo)      * 512 + ic + colo, Bs + r0 * 32);
            gld16(Bb + (size_t)(r0 + 16 + rlo) * 512 + ic + colo, Bs + (r0 + 16) * 32);
            __syncthreads();
            short8 a0 = *(const short8*)&As[(r0 + l15) * 32 + sgf];
            short8 a1 = *(const short8*)&As[(r0 + 16 + l15) * 32 + sgf];
            #pragma unroll
            for (int f = 0; f < 8; ++f){
                short8 b = *(const short8*)&Bs[(f * 16 + l15) * 32 + sgf];
                acc[0][f] = __builtin_amdgcn_mfma_f32_16x16x32_bf16(a0, b, acc[0][f], 0, 0, 0);
                acc[1][f] = __builtin_amdgcn_mfma_f32_16x16x32_bf16(a1, b, acc[1][f], 0, 0, 0);
            }
            __syncthreads();
        }
    }
    float gs = 0.f, gq = 0.f;
    int sg = tid & 15;
    #pragma unroll
    for (int pass = 0; pass < 4; ++pass){
        __syncthreads();
        #pragma unroll
        for (int m = 0; m < 2; ++m){
            #pragma unroll
            for (int fi = 0; fi < 2; ++fi){
                int f = pass * 2 + fi;
                int tl = fi * 16 + l15;
                int ob = wid * 32 + m * 16 + quad * 4;
                #pragma unroll
                for (int r = 0; r < 4; ++r)
                    Lt[tl * 132 + ob + r] = acc[m][f][r] + bias[o0 + ob + r];
            }
        }
        __syncthreads();
        #pragma unroll
        for (int it = 0; it < 2; ++it){
            int p = tid + it * 256;
            int tl = p >> 4, s = p & 15;
            short8 sv;
            #pragma unroll
            for (int j = 0; j < 8; ++j){
                float fv = Lt[tl * 132 + s * 8 + j];
                gs += fv; gq += fv * fv;
                sv[j] = f2s(fv);
            }
            *(short8*)&ht[((size_t)n * Tt + t0 + pass * 32 + tl) * Cc + o0 + s * 8] = sv;
        }
    }
    if (tid < 16) gred[tid] = 0.f;
    __syncthreads();
    atomicAdd(&gred[(sg >> 1) * 2 + 0], gs);
    atomicAdd(&gred[(sg >> 1) * 2 + 1], gq);
    __syncthreads();
    if (tid < 8){
        int blk = n * 32 + (o0 >> 4) + tid;
        atomicAdd(&gsum[blk], gred[tid * 2 + 0]);
        atomicAdd(&gss[blk],  gred[tid * 2 + 1]);
    }
}

// ---- GN apply + relu, in place on ht (stats from fused sums) ----
__global__ void k_gnapply2(bf16* __restrict__ ht, const float* __restrict__ gsum,
        const float* __restrict__ gss, const float* __restrict__ gamma,
        const float* __restrict__ beta){
    int p = blockIdx.x * 256 + threadIdx.x;
    int s = p & 63, row = p >> 6;             // row = n*4096+t
    int n = row >> 12;
    int ib = s * 8;
    int blk = n * 32 + (ib >> 4);
    const float inv = 1.f / (float)(CPG * Tt);
    float mu = gsum[blk] * inv;
    float rs = rsqrtf(gss[blk] * inv - mu * mu + EPS);
    short8 v = *(short8*)&ht[(size_t)row * Cc + ib];
    short8 o;
    #pragma unroll
    for (int j = 0; j < 8; ++j){
        int c = ib + j;
        float f = (s2f(v[j]) - mu) * rs * gamma[c] + beta[c];
        o[j] = f2s(fmaxf(f, 0.f));
    }
    *(short8*)&ht[(size_t)row * Cc + ib] = o;
}

// ---- materialize S0/S2 (gather+lerp, coalesced in i); prep inlined;
//      XCD-contiguity swizzle on t-chunks ----
__global__ void k_sample(const bf16* __restrict__ ht, const float* __restrict__ locs,
        const void* __restrict__ sp, bf16* __restrict__ S0, bf16* __restrict__ S2){
    int n = blockIdx.y;
    int bx = blockIdx.x;
    int t0 = ((((bx & 7) << 5) | (bx >> 3))) << 4;   // bijective on 256 chunks
    int lane = threadIdx.x & 63, slot = threadIdx.x >> 6;
    float s = stride_val(sp);
    const bf16* hb = ht + (size_t)n * Tt * Cc;
    #pragma unroll
    for (int rr = 0; rr < 4; ++rr){
        int t = t0 + slot * 4 + rr;
        int idx = n * Tt + t;
        float l1 = locs[((size_t)n * 2 + 0) * Tt + t];
        float l2 = locs[((size_t)n * 2 + 1) * Tt + t];
        float y1 = (0.9f * l1 + 0.1f * l1) / s;     // match ref GRAD_MUL arithmetic
        float y2 = (0.9f * l2 + 0.1f * l2) / s;
        {
            float pos0 = (float)(t - 1) - y1;
            float p0f = floorf(pos0);
            float w1 = pos0 - p0f;
            int a0 = (int)p0f, a1 = a0 + 1;
            float w0 = (a0 >= 0 && a0 < Tt) ? (1.f - w1) : 0.f;
            float w1v = (a1 >= 0 && a1 < Tt) ? w1 : 0.f;
            int ia0 = min(max(a0, 0), Tt - 1);
            int ia1 = min(max(a1, 0), Tt - 1);
            short8 lo = *(const short8*)&hb[(size_t)ia0 * Cc + lane * 8];
            short8 hi = *(const short8*)&hb[(size_t)ia1 * Cc + lane * 8];
            short8 o;
            #pragma unroll
            for (int j = 0; j < 8; ++j) o[j] = f2s(w0 * s2f(lo[j]) + w1v * s2f(hi[j]));
            *(short8*)&S0[(size_t)idx * Cc + lane * 8] = o;
        }
        {
            float pos2 = (float)(t + 1) + y2;
            float p2f = floorf(pos2);
            float w2 = pos2 - p2f;
            int c0 = (int)p2f, c1 = c0 + 1;
            float w0 = (c0 >= 0 && c0 < Tt) ? (1.f - w2) : 0.f;
            float w1v = (c1 >= 0 && c1 < Tt) ? w2 : 0.f;
            int ic0 = min(max(c0, 0), Tt - 1);
            int ic1 = min(max(c1, 0), Tt - 1);
            short8 lo = *(const short8*)&hb[(size_t)ic0 * Cc + lane * 8];
            short8 hi = *(const short8*)&hb[(size_t)ic1 * Cc + lane * 8];
            short8 o;
            #pragma unroll
            for (int j = 0; j < 8; ++j) o[j] = f2s(w0 * s2f(lo[j]) + w1v * s2f(hi[j]));
            *(short8*)&S2[(size_t)idx * Cc + lane * 8] = o;
        }
    }
}

// ---- deform GEMM (BK=64 core, R8-proven) + fused out-conv scatter epilogue ----
__global__ __launch_bounds__(256, 4) void k_deformg(const bf16* __restrict__ S0,
        const bf16* __restrict__ ht, const bf16* __restrict__ S2,
        const bf16* __restrict__ wtd, const float* __restrict__ bias,
        float* __restrict__ out, const float* __restrict__ wout,
        float* __restrict__ oout){
    __shared__ __align__(16) short SM[4][128 * 32];  // A0,A1,B0,B1 = 32 KiB
    int t0 = blockIdx.x * 128, o0 = blockIdx.y * 128, n = blockIdx.z;
    int tid = threadIdx.x, wid = tid >> 6, lane = tid & 63;
    int quad = lane >> 4, l15 = lane & 15;
    int rlo  = lane >> 2;
    int colo = 8 * ((lane & 3) ^ ((lane >> 3) & 3));
    int sgf  = 8 * (quad ^ ((lane >> 1) & 3));

    float4v acc[2][8];
    #pragma unroll
    for (int m = 0; m < 2; ++m)
        #pragma unroll
        for (int f = 0; f < 8; ++f) acc[m][f] = (float4v){0.f,0.f,0.f,0.f};

    size_t boff = ((size_t)n * Tt + t0) * 512;
    const short* Bb3[3] = { (const short*)S0 + boff, (const short*)ht + boff,
                            (const short*)S2 + boff };
    const short* ABp = (const short*)wtd + (size_t)o0 * 512;
    int r0 = wid * 32;

    for (int tap = 0; tap < 3; ++tap){
        const short* Ab = ABp + (size_t)tap * 262144;
        const short* Bb = Bb3[tap];
        for (int ic = 0; ic < 512; ic += 64){
            gld16(Ab + (size_t)(r0 + rlo)      * 512 + ic      + colo, &SM[0][r0 * 32]);
            gld16(Ab + (size_t)(r0 + 16 + rlo) * 512 + ic      + colo, &SM[0][(r0 + 16) * 32]);
            gld16(Ab + (size_t)(r0 + rlo)      * 512 + ic + 32 + colo, &SM[1][r0 * 32]);
            gld16(Ab + (size_t)(r0 + 16 + rlo) * 512 + ic + 32 + colo, &SM[1][(r0 + 16) * 32]);
            gld16(Bb + (size_t)(r0 + rlo)      * 512 + ic      + colo, &SM[2][r0 * 32]);
            gld16(Bb + (size_t)(r0 + 16 + rlo) * 512 + ic      + colo, &SM[2][(r0 + 16) * 32]);
            gld16(Bb + (size_t)(r0 + rlo)      * 512 + ic + 32 + colo, &SM[3][r0 * 32]);
            gld16(Bb + (size_t)(r0 + 16 + rlo) * 512 + ic + 32 + colo, &SM[3][(r0 + 16) * 32]);
            __syncthreads();
            #pragma unroll
            for (int kk = 0; kk < 2; ++kk){
                const short* Ah = SM[kk];
                const short* Bh = SM[2 + kk];
                short8 a0 = *(const short8*)&Ah[(r0 + l15) * 32 + sgf];
                short8 a1 = *(const short8*)&Ah[(r0 + 16 + l15) * 32 + sgf];
                #pragma unroll
                for (int f = 0; f < 8; ++f){
                    short8 b = *(const short8*)&Bh[(f * 16 + l15) * 32 + sgf];
                    acc[0][f] = __builtin_amdgcn_mfma_f32_16x16x32_bf16(a0, b, acc[0][f], 0, 0, 0);
                    acc[1][f] = __builtin_amdgcn_mfma_f32_16x16x32_bf16(a1, b, acc[1][f], 0, 0, 0);
                }
            }
            __syncthreads();
        }
    }
    // epilogue A: relu(acc+bias) -> offset_feat, keep v in acc for scatter
    float* part = (float*)SM;   // [2][132] (safe: K-loop ended with barrier)
    for (int q = tid; q < 264; q += 256) part[q] = 0.f;
    float* ob = out + (size_t)n * Cc * Tt;
    #pragma unroll
    for (int m = 0; m < 2; ++m){
        int ob0 = o0 + wid * 32 + m * 16 + quad * 4;
        #pragma unroll
        for (int r = 0; r < 4; ++r){
            float bs = bias[ob0 + r];
            size_t row = (size_t)(ob0 + r) * Tt;
            #pragma unroll
            for (int f = 0; f < 8; ++f){
                float v = fmaxf(acc[m][f][r] + bs, 0.f);
                acc[m][f][r] = v;
                ob[row + t0 + f * 16 + l15] = v;
            }
        }
    }
    __syncthreads();
    // epilogue B: scatter out-conv; wout read direct (16-way L1 broadcast)
    #pragma unroll
    for (int c = 0; c < 2; ++c){
        float wr[3][2][4];
        #pragma unroll
        for (int m = 0; m < 2; ++m){
            int ob0 = o0 + wid * 32 + m * 16 + quad * 4;
            #pragma unroll
            for (int r = 0; r < 4; ++r){
                const float* wp = wout + (size_t)c * 1536 + (ob0 + r) * 3;
                wr[0][m][r] = wp[0];
                wr[1][m][r] = wp[1];
                wr[2][m][r] = wp[2];
            }
        }
        #pragma unroll
        for (int f = 0; f < 8; ++f){
            #pragma unroll
            for (int k = 0; k < 3; ++k){
                float contrib = 0.f;
                #pragma unroll
                for (int m = 0; m < 2; ++m)
                    #pragma unroll
                    for (int r = 0; r < 4; ++r)
                        contrib += wr[k][m][r] * acc[m][f][r];
                contrib += __shfl_xor(contrib, 16);
                contrib += __shfl_xor(contrib, 32);
                if (quad == 0)
                    atomicAdd(&part[c * 132 + f * 16 + l15 + 2 - k], contrib);
            }
        }
    }
    __syncthreads();
    for (int q = tid; q < 264; q += 256){
        int c = q / 132, tl = q - c * 132;
        if (tl < 130){
            int tg = t0 + tl - 1;
            if (tg >= 0 && tg < Tt)
                atomicAdd(&oout[((size_t)n * 2 + c) * Tt + tg], part[q]);
        }
    }
}

// ================================ HOST ================================
extern "C" void kernel_launch(void* const* d_in, const int* in_sizes, int n_in,
                              void* d_out, int out_size, void* d_ws, size_t ws_size,
                              hipStream_t stream) {
    const float* feat   = (const float*)d_in[0];
    const float* locs   = (const float*)d_in[1];
    const float* conv_w = (const float*)d_in[2];
    const float* conv_b = (const float*)d_in[3];
    const float* gn_g   = (const float*)d_in[4];
    const float* gn_b   = (const float*)d_in[5];
    const float* dcn_w  = (const float*)d_in[6];
    const float* dcn_b  = (const float*)d_in[7];
    const float* out_w  = (const float*)d_in[8];
    const float* out_b  = (const float*)d_in[9];

    float* offset      = (float*)d_out;                        // (8,2,4096) fp32
    float* offset_feat = (float*)d_out + (size_t)Nn * 2 * Tt;  // (8,512,4096) fp32

    constexpr size_t OFF_WTC  = 4096;
    constexpr size_t OFF_WTD  = OFF_WTC + 3 * 512 * 512 * 2;
    constexpr size_t OFF_FTR  = OFF_WTD + 3 * 512 * 512 * 2;
    constexpr size_t OFF_HT   = OFF_FTR + (size_t)8 * 4098 * 512 * 2;
    constexpr size_t OFF_S2   = OFF_HT  + (size_t)8 * 4096 * 512 * 2;

    float* gsum = (float*)d_ws;                       // 256 floats
    float* gss  = (float*)((char*)d_ws + 1024);       // 256 floats

    char* ws = (char*)d_ws;
    bf16* wtc = (bf16*)(ws + OFF_WTC);
    bf16* wtd = (bf16*)(ws + OFF_WTD);
    bf16* ftr = (bf16*)(ws + OFF_FTR);    // reused as S0 after conv1
    bf16* ht  = (bf16*)(ws + OFF_HT);
    bf16* S2  = (bf16*)(ws + OFF_S2);
    bf16* S0  = ftr;

    k_transpose<<<dim3(64, 8, 8), 256, 0, stream>>>(feat, ftr);
    k_misc     <<<3072, 256, 0, stream>>>(conv_w, dcn_w, wtc, wtd, ftr, out_b,
                                          offset, (float*)d_ws);
    k_conv1g   <<<dim3(32, 4, 8), 256, 0, stream>>>(ftr, wtc, conv_b, ht, gsum, gss);
    k_gnapply2 <<<8192, 256, 0, stream>>>(ht, gsum, gss, gn_g, gn_b);
    k_sample   <<<dim3(256, 8), 256, 0, stream>>>(ht, locs, d_in[10], S0, S2);
    k_deformg  <<<dim3(32, 4, 8), 256, 0, stream>>>(S0, ht, S2, wtd, dcn_b,
                                                    offset_feat, out_w, offset);
}

// Round 11
// 297.609 us; speedup vs baseline: 1.0373x; 1.0064x over previous
//
#include <hip/hip_runtime.h>
#include <hip/hip_bf16.h>

typedef __hip_bfloat16 bf16;
typedef __attribute__((ext_vector_type(8))) short short8;
typedef __attribute__((ext_vector_type(4))) float float4v;

constexpr int Nn = 8, Cc = 512, Tt = 4096, Gg = 32, CPG = 16;
constexpr float EPS = 1e-5f;

__device__ __forceinline__ float b2f(bf16 x){ return __bfloat162float(x); }
__device__ __forceinline__ bf16  f2b(float x){ return __float2bfloat16(x); }
__device__ __forceinline__ short f2s(float x){
    union { bf16 b; short s; } u; u.b = f2b(x); return u.s;
}
__device__ __forceinline__ float s2f(short x){
    union { short s; bf16 b; } u; u.s = x; return b2f(u.b);
}

__device__ __forceinline__ float stride_val(const void* sp){
    int si = *(const int*)sp;
    if (si >= 1 && si <= 100000) return (float)si;
    float sf = *(const float*)sp;
    if (sf >= 0.5f && sf <= 1.0e5f) return sf;
    return 8.0f;
}

// async global->LDS, 16B per lane; LDS dest = wave-uniform base + lane*16
__device__ __forceinline__ void gld16(const void* g, void* l){
    __builtin_amdgcn_global_load_lds(
        (const __attribute__((address_space(1))) unsigned int*)g,
        (__attribute__((address_space(3))) unsigned int*)l, 16, 0, 0);
}

// ---- P1: transpose feat fp32 [n][i][t] -> ftr bf16 [n][t+1][i] (pad rows 0,4097) ----
__global__ void k_transpose(const float* __restrict__ feat, bf16* __restrict__ ftr){
    __shared__ float L[64 * 65];
    int t0 = blockIdx.x * 64, i0 = blockIdx.y * 64, n = blockIdx.z;
    int tid = threadIdx.x;
    const float* fb = feat + ((size_t)n * Cc + i0) * Tt + t0;
    #pragma unroll
    for (int it = 0; it < 4; ++it){
        int p = tid + it * 256;
        int i = p >> 4, t4 = (p & 15) * 4;
        float4v v = *(const float4v*)&fb[(size_t)i * Tt + t4];
        L[(t4 + 0) * 65 + i] = v.x;
        L[(t4 + 1) * 65 + i] = v.y;
        L[(t4 + 2) * 65 + i] = v.z;
        L[(t4 + 3) * 65 + i] = v.w;
    }
    __syncthreads();
    #pragma unroll
    for (int it = 0; it < 2; ++it){
        int p = tid + it * 256;
        int t = p >> 3, s = p & 7;
        short8 sv;
        #pragma unroll
        for (int j = 0; j < 8; ++j) sv[j] = f2s(L[t * 65 + s * 8 + j]);
        *(short8*)&ftr[((size_t)n * 4098 + t0 + t + 1) * Cc + i0 + s * 8] = sv;
    }
}

// ---- merged small kernels: weight cvt x2, ftr zero-pad, offset init, stat zero ----
__global__ void k_misc(const float* __restrict__ cw, const float* __restrict__ dw,
        bf16* __restrict__ wtc, bf16* __restrict__ wtd, bf16* __restrict__ ftr,
        const float* __restrict__ ob, float* __restrict__ offset,
        float* __restrict__ gstat){
    int p = blockIdx.x * 256 + threadIdx.x;      // 786432
    {
        int k = p >> 18, rest = p & 262143;
        wtc[p] = f2b(cw[(size_t)rest * 3 + k]);
        wtd[p] = f2b(dw[(size_t)rest * 3 + k]);
    }
    if (p < 65536) offset[p] = ob[(p >> 12) & 1];
    if (p < 8192){
        int n = p >> 10, r = (p >> 9) & 1, i = p & 511;
        ftr[((size_t)n * 4098 + (r ? 4097 : 0)) * Cc + i] = f2b(0.f);
    }
    if (p < 512) gstat[p] = 0.f;
}

// =====================================================================
// conv1 GEMM: BK=32 core (A/B-proven best for conv1g)
// LDS(r,s) holds G(r, s ^ ((r>>1)&3)); frag read uses same xor.
// =====================================================================
__global__ __launch_bounds__(256, 4) void k_conv1g(const bf16* __restrict__ ftr,
        const bf16* __restrict__ wtc, const float* __restrict__ bias, bf16* __restrict__ ht,
        float* __restrict__ gsum, float* __restrict__ gss){
    __shared__ __align__(16) short As[128 * 32];
    __shared__ __align__(16) short Bs[128 * 32];
    __shared__ float Lt[32 * 132];
    __shared__ float gred[16];
    int t0 = blockIdx.x * 128, o0 = blockIdx.y * 128, n = blockIdx.z;
    int tid = threadIdx.x, wid = tid >> 6, lane = tid & 63;
    int quad = lane >> 4, l15 = lane & 15;
    int rlo  = lane >> 2;                            // staging row within 16
    int colo = 8 * ((lane & 3) ^ ((lane >> 3) & 3)); // swizzled staging col (shorts)
    int sgf  = 8 * (quad ^ ((lane >> 1) & 3));       // swizzled frag col (shorts)

    float4v acc[2][8];
    #pragma unroll
    for (int m = 0; m < 2; ++m)
        #pragma unroll
        for (int f = 0; f < 8; ++f) acc[m][f] = (float4v){0.f,0.f,0.f,0.f};

    const short* ABp = (const short*)wtc + (size_t)o0 * 512;
    const short* BBp = (const short*)ftr + ((size_t)n * 4098 + t0) * 512;
    int r0 = wid * 32;

    for (int tap = 0; tap < 3; ++tap){
        const short* Ab = ABp + (size_t)tap * 262144;
        const short* Bb = BBp + (size_t)tap * 512;
        for (int ic = 0; ic < 512; ic += 32){
            gld16(Ab + (size_t)(r0 + rlo)      * 512 + ic + colo, As + r0 * 32);
            gld16(Ab + (size_t)(r0 + 16 + rlo) * 512 + ic + colo, As + (r0 + 16) * 32);
            gld16(Bb + (size_t)(r0 + rlo)      * 512 + ic + colo, Bs + r0 * 32);
            gld16(Bb + (size_t)(r0 + 16 + rlo) * 512 + ic + colo, Bs + (r0 + 16) * 32);
            __syncthreads();
            short8 a0 = *(const short8*)&As[(r0 + l15) * 32 + sgf];
            short8 a1 = *(const short8*)&As[(r0 + 16 + l15) * 32 + sgf];
            #pragma unroll
            for (int f = 0; f < 8; ++f){
                short8 b = *(const short8*)&Bs[(f * 16 + l15) * 32 + sgf];
                acc[0][f] = __builtin_amdgcn_mfma_f32_16x16x32_bf16(a0, b, acc[0][f], 0, 0, 0);
                acc[1][f] = __builtin_amdgcn_mfma_f32_16x16x32_bf16(a1, b, acc[1][f], 0, 0, 0);
            }
            __syncthreads();
        }
    }
    float gs = 0.f, gq = 0.f;
    int sg = tid & 15;
    #pragma unroll
    for (int pass = 0; pass < 4; ++pass){
        __syncthreads();
        #pragma unroll
        for (int m = 0; m < 2; ++m){
            #pragma unroll
            for (int fi = 0; fi < 2; ++fi){
                int f = pass * 2 + fi;
                int tl = fi * 16 + l15;
                int ob = wid * 32 + m * 16 + quad * 4;
                #pragma unroll
                for (int r = 0; r < 4; ++r)
                    Lt[tl * 132 + ob + r] = acc[m][f][r] + bias[o0 + ob + r];
            }
        }
        __syncthreads();
        #pragma unroll
        for (int it = 0; it < 2; ++it){
            int p = tid + it * 256;
            int tl = p >> 4, s = p & 15;
            short8 sv;
            #pragma unroll
            for (int j = 0; j < 8; ++j){
                float fv = Lt[tl * 132 + s * 8 + j];
                gs += fv; gq += fv * fv;
                sv[j] = f2s(fv);
            }
            *(short8*)&ht[((size_t)n * Tt + t0 + pass * 32 + tl) * Cc + o0 + s * 8] = sv;
        }
    }
    if (tid < 16) gred[tid] = 0.f;
    __syncthreads();
    atomicAdd(&gred[(sg >> 1) * 2 + 0], gs);
    atomicAdd(&gred[(sg >> 1) * 2 + 1], gq);
    __syncthreads();
    if (tid < 8){
        int blk = n * 32 + (o0 >> 4) + tid;
        atomicAdd(&gsum[blk], gred[tid * 2 + 0]);
        atomicAdd(&gss[blk],  gred[tid * 2 + 1]);
    }
}

// ---- GN apply + relu, in place on ht (fallback path if ws too small) ----
__global__ void k_gnapply2(bf16* __restrict__ ht, const float* __restrict__ gsum,
        const float* __restrict__ gss, const float* __restrict__ gamma,
        const float* __restrict__ beta){
    int p = blockIdx.x * 256 + threadIdx.x;
    int s = p & 63, row = p >> 6;             // row = n*4096+t
    int n = row >> 12;
    int ib = s * 8;
    int blk = n * 32 + (ib >> 4);
    const float inv = 1.f / (float)(CPG * Tt);
    float mu = gsum[blk] * inv;
    float rs = rsqrtf(gss[blk] * inv - mu * mu + EPS);
    short8 v = *(short8*)&ht[(size_t)row * Cc + ib];
    short8 o;
    #pragma unroll
    for (int j = 0; j < 8; ++j){
        int c = ib + j;
        float f = (s2f(v[j]) - mu) * rs * gamma[c] + beta[c];
        o[j] = f2s(fmaxf(f, 0.f));
    }
    *(short8*)&ht[(size_t)row * Cc + ib] = o;
}

// ---- fallback sample (reads pre-normalized ht; R10-exact) ----
__global__ void k_sample(const bf16* __restrict__ ht, const float* __restrict__ locs,
        const void* __restrict__ sp, bf16* __restrict__ S0, bf16* __restrict__ S2){
    int n = blockIdx.y;
    int bx = blockIdx.x;
    int t0 = ((((bx & 7) << 5) | (bx >> 3))) << 4;   // bijective on 256 chunks
    int lane = threadIdx.x & 63, slot = threadIdx.x >> 6;
    float s = stride_val(sp);
    const bf16* hb = ht + (size_t)n * Tt * Cc;
    #pragma unroll
    for (int rr = 0; rr < 4; ++rr){
        int t = t0 + slot * 4 + rr;
        int idx = n * Tt + t;
        float l1 = locs[((size_t)n * 2 + 0) * Tt + t];
        float l2 = locs[((size_t)n * 2 + 1) * Tt + t];
        float y1 = (0.9f * l1 + 0.1f * l1) / s;
        float y2 = (0.9f * l2 + 0.1f * l2) / s;
        {
            float pos0 = (float)(t - 1) - y1;
            float p0f = floorf(pos0);
            float w1 = pos0 - p0f;
            int a0 = (int)p0f, a1 = a0 + 1;
            float w0 = (a0 >= 0 && a0 < Tt) ? (1.f - w1) : 0.f;
            float w1v = (a1 >= 0 && a1 < Tt) ? w1 : 0.f;
            int ia0 = min(max(a0, 0), Tt - 1);
            int ia1 = min(max(a1, 0), Tt - 1);
            short8 lo = *(const short8*)&hb[(size_t)ia0 * Cc + lane * 8];
            short8 hi = *(const short8*)&hb[(size_t)ia1 * Cc + lane * 8];
            short8 o;
            #pragma unroll
            for (int j = 0; j < 8; ++j) o[j] = f2s(w0 * s2f(lo[j]) + w1v * s2f(hi[j]));
            *(short8*)&S0[(size_t)idx * Cc + lane * 8] = o;
        }
        {
            float pos2 = (float)(t + 1) + y2;
            float p2f = floorf(pos2);
            float w2 = pos2 - p2f;
            int c0 = (int)p2f, c1 = c0 + 1;
            float w0 = (c0 >= 0 && c0 < Tt) ? (1.f - w2) : 0.f;
            float w1v = (c1 >= 0 && c1 < Tt) ? w2 : 0.f;
            int ic0 = min(max(c0, 0), Tt - 1);
            int ic1 = min(max(c1, 0), Tt - 1);
            short8 lo = *(const short8*)&hb[(size_t)ic0 * Cc + lane * 8];
            short8 hi = *(const short8*)&hb[(size_t)ic1 * Cc + lane * 8];
            short8 o;
            #pragma unroll
            for (int j = 0; j < 8; ++j) o[j] = f2s(w0 * s2f(lo[j]) + w1v * s2f(hi[j]));
            *(short8*)&S2[(size_t)idx * Cc + lane * 8] = o;
        }
    }
}

// ---- fused sample: GN+relu applied on the fly from RAW ht; also emits
//      htn[t] = relu(norm(ht[t])) for deformg's tap-1. Replaces k_gnapply2.
//      nr(v) = v*a + b per channel (a = rs*gamma, b = beta - mu*rs*gamma);
//      relu before lerp preserves ref order; OOB masking via zeroed weights. ----
__global__ void k_sample_f(const bf16* __restrict__ ht, const float* __restrict__ locs,
        const void* __restrict__ sp, const float* __restrict__ gsum,
        const float* __restrict__ gss, const float* __restrict__ gamma,
        const float* __restrict__ beta, bf16* __restrict__ S0, bf16* __restrict__ S2,
        bf16* __restrict__ htn){
    int n = blockIdx.y;
    int bx = blockIdx.x;
    int t0 = ((((bx & 7) << 5) | (bx >> 3))) << 4;   // bijective on 256 chunks
    int lane = threadIdx.x & 63, slot = threadIdx.x >> 6;
    float s = stride_val(sp);
    const bf16* hb = ht + (size_t)n * Tt * Cc;
    // per-lane channel-affine coefficients (8 channels, single GN group)
    int ch0 = lane * 8;
    int blk = n * 32 + (ch0 >> 4);
    const float inv = 1.f / (float)(CPG * Tt);
    float mu = gsum[blk] * inv;
    float rs = rsqrtf(gss[blk] * inv - mu * mu + EPS);
    float av[8], bv[8];
    #pragma unroll
    for (int j = 0; j < 8; ++j){
        float g = gamma[ch0 + j];
        av[j] = rs * g;
        bv[j] = beta[ch0 + j] - mu * rs * g;
    }
    #pragma unroll
    for (int rr = 0; rr < 4; ++rr){
        int t = t0 + slot * 4 + rr;
        int idx = n * Tt + t;
        float l1 = locs[((size_t)n * 2 + 0) * Tt + t];
        float l2 = locs[((size_t)n * 2 + 1) * Tt + t];
        float y1 = (0.9f * l1 + 0.1f * l1) / s;     // match ref GRAD_MUL arithmetic
        float y2 = (0.9f * l2 + 0.1f * l2) / s;
        // own row -> htn
        {
            short8 ow = *(const short8*)&hb[(size_t)t * Cc + ch0];
            short8 o;
            #pragma unroll
            for (int j = 0; j < 8; ++j)
                o[j] = f2s(fmaxf(fmaf(s2f(ow[j]), av[j], bv[j]), 0.f));
            *(short8*)&htn[(size_t)idx * Cc + ch0] = o;
        }
        {
            float pos0 = (float)(t - 1) - y1;
            float p0f = floorf(pos0);
            float w1 = pos0 - p0f;
            int a0 = (int)p0f, a1 = a0 + 1;
            float w0 = (a0 >= 0 && a0 < Tt) ? (1.f - w1) : 0.f;
            float w1v = (a1 >= 0 && a1 < Tt) ? w1 : 0.f;
            int ia0 = min(max(a0, 0), Tt - 1);
            int ia1 = min(max(a1, 0), Tt - 1);
            short8 lo = *(const short8*)&hb[(size_t)ia0 * Cc + ch0];
            short8 hi = *(const short8*)&hb[(size_t)ia1 * Cc + ch0];
            short8 o;
            #pragma unroll
            for (int j = 0; j < 8; ++j){
                float nl = fmaxf(fmaf(s2f(lo[j]), av[j], bv[j]), 0.f);
                float nh = fmaxf(fmaf(s2f(hi[j]), av[j], bv[j]), 0.f);
                o[j] = f2s(w0 * nl + w1v * nh);
            }
            *(short8*)&S0[(size_t)idx * Cc + ch0] = o;
        }
        {
            float pos2 = (float)(t + 1) + y2;
            float p2f = floorf(pos2);
            float w2 = pos2 - p2f;
            int c0 = (int)p2f, c1 = c0 + 1;
            float w0 = (c0 >= 0 && c0 < Tt) ? (1.f - w2) : 0.f;
            float w1v = (c1 >= 0 && c1 < Tt) ? w2 : 0.f;
            int ic0 = min(max(c0, 0), Tt - 1);
            int ic1 = min(max(c1, 0), Tt - 1);
            short8 lo = *(const short8*)&hb[(size_t)ic0 * Cc + ch0];
            short8 hi = *(const short8*)&hb[(size_t)ic1 * Cc + ch0];
            short8 o;
            #pragma unroll
            for (int j = 0; j < 8; ++j){
                float nl = fmaxf(fmaf(s2f(lo[j]), av[j], bv[j]), 0.f);
                float nh = fmaxf(fmaf(s2f(hi[j]), av[j], bv[j]), 0.f);
                o[j] = f2s(w0 * nl + w1v * nh);
            }
            *(short8*)&S2[(size_t)idx * Cc + ch0] = o;
        }
    }
}

// ---- deform GEMM (BK=64 core, R8-proven) + fused out-conv scatter epilogue ----
__global__ __launch_bounds__(256, 4) void k_deformg(const bf16* __restrict__ S0,
        const bf16* __restrict__ ht, const bf16* __restrict__ S2,
        const bf16* __restrict__ wtd, const float* __restrict__ bias,
        float* __restrict__ out, const float* __restrict__ wout,
        float* __restrict__ oout){
    __shared__ __align__(16) short SM[4][128 * 32];  // A0,A1,B0,B1 = 32 KiB
    int t0 = blockIdx.x * 128, o0 = blockIdx.y * 128, n = blockIdx.z;
    int tid = threadIdx.x, wid = tid >> 6, lane = tid & 63;
    int quad = lane >> 4, l15 = lane & 15;
    int rlo  = lane >> 2;
    int colo = 8 * ((lane & 3) ^ ((lane >> 3) & 3));
    int sgf  = 8 * (quad ^ ((lane >> 1) & 3));

    float4v acc[2][8];
    #pragma unroll
    for (int m = 0; m < 2; ++m)
        #pragma unroll
        for (int f = 0; f < 8; ++f) acc[m][f] = (float4v){0.f,0.f,0.f,0.f};

    size_t boff = ((size_t)n * Tt + t0) * 512;
    const short* Bb3[3] = { (const short*)S0 + boff, (const short*)ht + boff,
                            (const short*)S2 + boff };
    const short* ABp = (const short*)wtd + (size_t)o0 * 512;
    int r0 = wid * 32;

    for (int tap = 0; tap < 3; ++tap){
        const short* Ab = ABp + (size_t)tap * 262144;
        const short* Bb = Bb3[tap];
        for (int ic = 0; ic < 512; ic += 64){
            gld16(Ab + (size_t)(r0 + rlo)      * 512 + ic      + colo, &SM[0][r0 * 32]);
            gld16(Ab + (size_t)(r0 + 16 + rlo) * 512 + ic      + colo, &SM[0][(r0 + 16) * 32]);
            gld16(Ab + (size_t)(r0 + rlo)      * 512 + ic + 32 + colo, &SM[1][r0 * 32]);
            gld16(Ab + (size_t)(r0 + 16 + rlo) * 512 + ic + 32 + colo, &SM[1][(r0 + 16) * 32]);
            gld16(Bb + (size_t)(r0 + rlo)      * 512 + ic      + colo, &SM[2][r0 * 32]);
            gld16(Bb + (size_t)(r0 + 16 + rlo) * 512 + ic      + colo, &SM[2][(r0 + 16) * 32]);
            gld16(Bb + (size_t)(r0 + rlo)      * 512 + ic + 32 + colo, &SM[3][r0 * 32]);
            gld16(Bb + (size_t)(r0 + 16 + rlo) * 512 + ic + 32 + colo, &SM[3][(r0 + 16) * 32]);
            __syncthreads();
            #pragma unroll
            for (int kk = 0; kk < 2; ++kk){
                const short* Ah = SM[kk];
                const short* Bh = SM[2 + kk];
                short8 a0 = *(const short8*)&Ah[(r0 + l15) * 32 + sgf];
                short8 a1 = *(const short8*)&Ah[(r0 + 16 + l15) * 32 + sgf];
                #pragma unroll
                for (int f = 0; f < 8; ++f){
                    short8 b = *(const short8*)&Bh[(f * 16 + l15) * 32 + sgf];
                    acc[0][f] = __builtin_amdgcn_mfma_f32_16x16x32_bf16(a0, b, acc[0][f], 0, 0, 0);
                    acc[1][f] = __builtin_amdgcn_mfma_f32_16x16x32_bf16(a1, b, acc[1][f], 0, 0, 0);
                }
            }
            __syncthreads();
        }
    }
    // epilogue A: relu(acc+bias) -> offset_feat, keep v in acc for scatter
    float* part = (float*)SM;   // [2][132] (safe: K-loop ended with barrier)
    for (int q = tid; q < 264; q += 256) part[q] = 0.f;
    float* ob = out + (size_t)n * Cc * Tt;
    #pragma unroll
    for (int m = 0; m < 2; ++m){
        int ob0 = o0 + wid * 32 + m * 16 + quad * 4;
        #pragma unroll
        for (int r = 0; r < 4; ++r){
            float bs = bias[ob0 + r];
            size_t row = (size_t)(ob0 + r) * Tt;
            #pragma unroll
            for (int f = 0; f < 8; ++f){
                float v = fmaxf(acc[m][f][r] + bs, 0.f);
                acc[m][f][r] = v;
                ob[row + t0 + f * 16 + l15] = v;
            }
        }
    }
    __syncthreads();
    // epilogue B: scatter out-conv; wout read direct (16-way L1 broadcast)
    #pragma unroll
    for (int c = 0; c < 2; ++c){
        float wr[3][2][4];
        #pragma unroll
        for (int m = 0; m < 2; ++m){
            int ob0 = o0 + wid * 32 + m * 16 + quad * 4;
            #pragma unroll
            for (int r = 0; r < 4; ++r){
                const float* wp = wout + (size_t)c * 1536 + (ob0 + r) * 3;
                wr[0][m][r] = wp[0];
                wr[1][m][r] = wp[1];
                wr[2][m][r] = wp[2];
            }
        }
        #pragma unroll
        for (int f = 0; f < 8; ++f){
            #pragma unroll
            for (int k = 0; k < 3; ++k){
                float contrib = 0.f;
                #pragma unroll
                for (int m = 0; m < 2; ++m)
                    #pragma unroll
                    for (int r = 0; r < 4; ++r)
                        contrib += wr[k][m][r] * acc[m][f][r];
                contrib += __shfl_xor(contrib, 16);
                contrib += __shfl_xor(contrib, 32);
                if (quad == 0)
                    atomicAdd(&part[c * 132 + f * 16 + l15 + 2 - k], contrib);
            }
        }
    }
    __syncthreads();
    for (int q = tid; q < 264; q += 256){
        int c = q / 132, tl = q - c * 132;
        if (tl < 130){
            int tg = t0 + tl - 1;
            if (tg >= 0 && tg < Tt)
                atomicAdd(&oout[((size_t)n * 2 + c) * Tt + tg], part[q]);
        }
    }
}

// ================================ HOST ================================
extern "C" void kernel_launch(void* const* d_in, const int* in_sizes, int n_in,
                              void* d_out, int out_size, void* d_ws, size_t ws_size,
                              hipStream_t stream) {
    const float* feat   = (const float*)d_in[0];
    const float* locs   = (const float*)d_in[1];
    const float* conv_w = (const float*)d_in[2];
    const float* conv_b = (const float*)d_in[3];
    const float* gn_g   = (const float*)d_in[4];
    const float* gn_b   = (const float*)d_in[5];
    const float* dcn_w  = (const float*)d_in[6];
    const float* dcn_b  = (const float*)d_in[7];
    const float* out_w  = (const float*)d_in[8];
    const float* out_b  = (const float*)d_in[9];

    float* offset      = (float*)d_out;                        // (8,2,4096) fp32
    float* offset_feat = (float*)d_out + (size_t)Nn * 2 * Tt;  // (8,512,4096) fp32

    constexpr size_t SZ_HT   = (size_t)8 * 4096 * 512 * 2;     // 33.5 MB
    constexpr size_t OFF_WTC = 4096;
    constexpr size_t OFF_WTD = OFF_WTC + 3 * 512 * 512 * 2;
    constexpr size_t OFF_FTR = OFF_WTD + 3 * 512 * 512 * 2;
    constexpr size_t OFF_HT  = OFF_FTR + (size_t)8 * 4098 * 512 * 2;
    constexpr size_t OFF_S2  = OFF_HT  + SZ_HT;
    constexpr size_t OFF_HTN = OFF_S2  + SZ_HT;
    constexpr size_t NEED_F  = OFF_HTN + SZ_HT;                // fused-path high water

    float* gsum = (float*)d_ws;                       // 256 floats
    float* gss  = (float*)((char*)d_ws + 1024);       // 256 floats

    char* ws = (char*)d_ws;
    bf16* wtc = (bf16*)(ws + OFF_WTC);
    bf16* wtd = (bf16*)(ws + OFF_WTD);
    bf16* ftr = (bf16*)(ws + OFF_FTR);    // reused as S0 after conv1
    bf16* ht  = (bf16*)(ws + OFF_HT);
    bf16* S2  = (bf16*)(ws + OFF_S2);
    bf16* htn = (bf16*)(ws + OFF_HTN);
    bf16* S0  = ftr;

    k_transpose<<<dim3(64, 8, 8), 256, 0, stream>>>(feat, ftr);
    k_misc     <<<3072, 256, 0, stream>>>(conv_w, dcn_w, wtc, wtd, ftr, out_b,
                                          offset, (float*)d_ws);
    k_conv1g   <<<dim3(32, 4, 8), 256, 0, stream>>>(ftr, wtc, conv_b, ht, gsum, gss);
    if (ws_size >= NEED_F){
        // fused path: GN+relu folded into sampling; gnapply deleted
        k_sample_f<<<dim3(256, 8), 256, 0, stream>>>(ht, locs, d_in[10], gsum, gss,
                                                     gn_g, gn_b, S0, S2, htn);
        k_deformg <<<dim3(32, 4, 8), 256, 0, stream>>>(S0, htn, S2, wtd, dcn_b,
                                                       offset_feat, out_w, offset);
    } else {
        // fallback: R10-proven 3-kernel path
        k_gnapply2<<<8192, 256, 0, stream>>>(ht, gsum, gss, gn_g, gn_b);
        k_sample  <<<dim3(256, 8), 256, 0, stream>>>(ht, locs, d_in[10], S0, S2);
        k_deformg <<<dim3(32, 4, 8), 256, 0, stream>>>(S0, ht, S2, wtd, dcn_b,
                                                       offset_feat, out_w, offset);
    }
}